// Round 4
// baseline (309.461 us; speedup 1.0000x reference)
//
#include <hip/hip_runtime.h>
#include <hip/hip_bf16.h>
#include <stdint.h>
#include <math.h>

// ---- problem constants ----
#define NB 16
#define NC 512
#define NH 64
#define NW 64
#define HW 4096            // NH*NW
#define TILE 16            // 16x16 pixel tile per block
#define HALO 24            // TILE + 8
#define HXP 32             // halo x padded to 32 (for two 16-wide N tiles)
#define KC 32              // channels per K chunk (one MFMA k-step)
#define NCH (NC / KC)      // 16 chunks
#define ROWB 80            // LDS bytes per pixel row: 32 bf16 = 64B + 16B pad (bank spread)
#define A_BASE 0
#define B_BASE (256 * ROWB)              // 20480
#define S_BASE (B_BASE + 768 * ROWB)     // 81920
#define LDS_BYTES (S_BASE + 1024 * 4)    // 86016

using f32x4  = __attribute__((ext_vector_type(4))) float;
using bf16x8 = __attribute__((ext_vector_type(8))) short;
using i32x4  = __attribute__((ext_vector_type(4))) int;

// fp32 -> bf16 bits, round-to-nearest-even (inputs are finite normals)
__device__ __forceinline__ unsigned bf16r(float x) {
  unsigned u = __float_as_uint(x);
  u += 0x7fffu + ((u >> 16) & 1u);
  return u >> 16;
}

__global__ __launch_bounds__(512, 2)
void corr_mfma(const float* __restrict__ f1, const float* __restrict__ f2,
               float* __restrict__ out)
{
  alignas(16) __shared__ unsigned char smem[LDS_BYTES];
  float* snorm = reinterpret_cast<float*>(smem + S_BASE);

  const int tid  = threadIdx.x;

  // ---- XCD-aware bijective remap (dispatch round-robins bid%8 across XCDs):
  // each XCD gets 2 complete batches -> all halo overlaps and half-line
  // partners are same-XCD L2 hits (2 MB/chunk working set < 4 MB L2).
  const int blk  = blockIdx.x;         // 0..255
  const int xcd  = blk & 7;
  const int slot = blk >> 3;           // 0..31
  const int b    = xcd * 2 + (slot >> 4);   // batch
  const int t4   = slot & 15;               // tile id within 4x4 grid
  const int y0   = (t4 >> 2) * TILE;
  const int x0   = (t4 & 3) * TILE;

  const int lane = tid & 63;
  const int lr   = lane & 15;          // frag row/col select
  const int lk   = lane >> 4;          // k-group (0..3)
  const int wv   = tid >> 6;           // wave id (0..7)

  // ---- per-thread staging slots: slot = tid and tid+512 ----
  // slots [0,256)   : f1 tile pixels   (ty = s>>4, tx = s&15)
  // slots [256,1024): f2 halo, h=s-256 (hy = h>>5, hx = h&31; hx>=24 is zero pad)
  const float* gptr[2];
  uint32_t     lbase[2];
  int          nidx[2];
  bool         ok[2];

  #pragma unroll
  for (int si = 0; si < 2; ++si) {
    const int s = tid + si * 512;
    nidx[si] = s;
    if (s < 256) {
      const int ty = s >> 4, tx = s & 15;
      gptr[si]  = f1 + (size_t)b * NC * HW + (size_t)(y0 + ty) * NW + (x0 + tx);
      lbase[si] = A_BASE + (uint32_t)s * ROWB;
      ok[si]    = true;
    } else {
      const int h  = s - 256;
      const int hy = h >> 5, hx = h & 31;
      const int yy = y0 - 4 + hy, xx = x0 - 4 + hx;
      const bool v = (hx < HALO) && ((unsigned)yy < NH) && ((unsigned)xx < NW);
      const size_t off = v ? ((size_t)b * NC * HW + (size_t)yy * NW + xx) : (size_t)0;
      gptr[si]  = f2 + off;
      lbase[si] = B_BASE + (uint32_t)h * ROWB;
      ok[si]    = v;
    }
  }

  // ---- accumulators: wave owns rows {2wv, 2wv+1} x 9 dh x 2 x'-tiles ----
  f32x4 acc[2][9][2];
  #pragma unroll
  for (int i = 0; i < 2; ++i)
    #pragma unroll
    for (int j = 0; j < 9; ++j)
      #pragma unroll
      for (int k = 0; k < 2; ++k) {
        f32x4 z = {0.f, 0.f, 0.f, 0.f};
        acc[i][j][k] = z;
      }

  float ss[2] = {0.f, 0.f};

  for (int kc = 0; kc < NCH; ++kc) {
    // ---------- stage chunk: global fp32 -> bf16 LDS [pixel][c], + sumsq ----------
    #pragma unroll
    for (int si = 0; si < 2; ++si) {
      const float* gp = gptr[si] + (size_t)kc * KC * HW;
      float v[KC];
      if (ok[si]) {
        #pragma unroll
        for (int k = 0; k < KC; ++k) v[k] = gp[(size_t)k * HW];
      } else {
        #pragma unroll
        for (int k = 0; k < KC; ++k) v[k] = 0.f;
      }
      float ps = 0.f;
      #pragma unroll
      for (int k = 0; k < KC; ++k) ps = fmaf(v[k], v[k], ps);
      ss[si] += ps;

      unsigned char* lp = smem + lbase[si];
      #pragma unroll
      for (int j = 0; j < 4; ++j) {
        i32x4 w;
        #pragma unroll
        for (int q = 0; q < 4; ++q) {
          const unsigned lo = bf16r(v[j * 8 + 2 * q]);
          const unsigned hi = bf16r(v[j * 8 + 2 * q + 1]);
          w[q] = (int)((hi << 16) | lo);
        }
        *reinterpret_cast<i32x4*>(lp + j * 16) = w;
      }
    }
    __syncthreads();

    // ---------- banded MFMA over this k-step ----------
    #pragma unroll
    for (int tyi = 0; tyi < 2; ++tyi) {
      const int ty = 2 * wv + tyi;
      const bf16x8 afr = *reinterpret_cast<const bf16x8*>(
          smem + A_BASE + (uint32_t)(ty * 16 + lr) * ROWB + lk * 16);
      #pragma unroll
      for (int dh = 0; dh < 9; ++dh) {
        const int hy = ty + dh;
        #pragma unroll
        for (int hx0 = 0; hx0 < 2; ++hx0) {
          const bf16x8 bfr = *reinterpret_cast<const bf16x8*>(
              smem + B_BASE + (uint32_t)(hy * HXP + hx0 * 16 + lr) * ROWB + lk * 16);
          acc[tyi][dh][hx0] =
              __builtin_amdgcn_mfma_f32_16x16x32_bf16(afr, bfr, acc[tyi][dh][hx0], 0, 0, 0);
        }
      }
    }
    __syncthreads();
  }

  // ---------- norms: snorm[i] = 1/sqrt(sumsq + 1e-6) ----------
  snorm[nidx[0]] = ss[0];
  snorm[nidx[1]] = ss[1];
  __syncthreads();
  #pragma unroll
  for (int i = 0; i < 2; ++i) {
    const int idx = tid + i * 512;
    snorm[idx] = 1.0f / sqrtf(snorm[idx] + 1e-6f);
  }
  __syncthreads();

  // ---------- epilogue: scale, relu, banded scatter ----------
  float* op = out + (size_t)b * 81 * HW;
  #pragma unroll
  for (int tyi = 0; tyi < 2; ++tyi) {
    const int ty = 2 * wv + tyi;
    #pragma unroll
    for (int dh = 0; dh < 9; ++dh) {
      const int hy = ty + dh;
      #pragma unroll
      for (int hx0 = 0; hx0 < 2; ++hx0) {
        const f32x4 a4 = acc[tyi][dh][hx0];
        const float i2 = snorm[256 + hy * HXP + hx0 * 16 + lr];  // lane's halo col
        #pragma unroll
        for (int r = 0; r < 4; ++r) {
          const int m  = lk * 4 + r;           // tile x (C/D row)
          const int dw = hx0 * 16 + lr - m;    // displacement = hx - tx
          if (dw >= 0 && dw < 9) {
            const float i1 = snorm[ty * 16 + m];
            float val = a4[r] * i1 * i2;
            val = fmaxf(val, 0.f);
            op[(size_t)(dh * 9 + dw) * HW + (size_t)(y0 + ty) * NW + (x0 + m)] = val;
          }
        }
      }
    }
  }
}

extern "C" void kernel_launch(void* const* d_in, const int* in_sizes, int n_in,
                              void* d_out, int out_size, void* d_ws, size_t ws_size,
                              hipStream_t stream) {
  (void)in_sizes; (void)n_in; (void)out_size; (void)d_ws; (void)ws_size;
  const float* f1 = (const float*)d_in[0];
  const float* f2 = (const float*)d_in[1];
  float* out = (float*)d_out;
  corr_mfma<<<dim3(256), dim3(512), 0, stream>>>(f1, f2, out);
}